// Round 6
// baseline (172.869 us; speedup 1.0000x reference)
//
#include <hip/hip_runtime.h>

typedef __attribute__((ext_vector_type(8))) short  s16x8;   // 8 x bf16
typedef __attribute__((ext_vector_type(4))) short  s16x4;
typedef __attribute__((ext_vector_type(4))) float  f32x4;

#define T_LEN 50000
#define S_LEN 168
#define W_IN  336
#define O_OUT 48
#define N_ROWS (T_LEN - W_IN - O_OUT + 1)   // 49617
#define N_PAD  49664                        // 776 * 64
#define NBLK   (N_PAD / 64)                 // 776

__device__ inline short f2bf(float f) {
    union { float f; unsigned u; } v; v.f = f;
    unsigned u = v.u;
    unsigned r = u + 0x7fffu + ((u >> 16) & 1u);   // RNE
    return (short)(r >> 16);
}

__device__ inline float readlane_f(float v, int l) {
    return __int_as_float(__builtin_amdgcn_readlane(__float_as_int(v), l));
}

__device__ inline float fast_tanh(float v) {
    float e = __expf(2.f * v);
    return 1.f - 2.f * __builtin_amdgcn_rcpf(e + 1.f);
}

// ---------------- pre-convert W1 -> W1T bf16 [352][352] (zero-padded), W2 -> W2T [48][360] --
__global__ void k_preconvert(const float* __restrict__ W1, const float* __restrict__ W2,
                             short* __restrict__ W1T, short* __restrict__ W2T) {
    int idx = blockIdx.x * 256 + threadIdx.x;
    const int n1 = 352 * 352;
    const int tot = n1 + 48 * 360;
    if (idx >= tot) return;
    if (idx < n1) {
        int j = idx / 352, k = idx % 352;
        W1T[idx] = (j < 336 && k < 336) ? f2bf(W1[k * 336 + j]) : (short)0;
    } else {
        int i2 = idx - n1;
        int o = i2 / 360, k = i2 % 360;
        W2T[i2] = (k < 336) ? f2bf(W2[k * 48 + o]) : (short)0;
    }
}

// ---------------- scan: chunk-64, ping-pong LDS regs, w-only ring, DPP scan ----------------
#define DPP_STEP(q_, CTRL, OMW) { \
    int t_ = __builtin_amdgcn_update_dpp(0, __float_as_int(q_), (CTRL), 0xf, 0xf, true); \
    q_ = fmaf((OMW), __int_as_float(t_), q_); }

__global__ void k_scan(const float* __restrict__ x, const float* __restrict__ level_sc,
                       const float* __restrict__ seas_sc, const float* __restrict__ init_seas,
                       float* __restrict__ levels, float* __restrict__ seas_full) {
    __shared__ float ring[256];      // ring[s & 255] = seas(s)
    int lane = threadIdx.x;          // 64 threads, 1 wave
    float a = 1.f / (1.f + expf(-level_sc[0]));
    float g = 1.f / (1.f + expf(-seas_sc[0]));
    float om = 1.f - a, omg = 1.f - g;

    for (int t = lane; t < 256; t += 64) {
        float s = 1.f;
        if (t <= S_LEN) { s = expf(init_seas[t < S_LEN ? t : 0]); seas_full[t] = s; }
        ring[t] = s;
    }
    float lpv = x[0] / expf(init_seas[0]);
    if (lane == 0) levels[0] = lpv;
    __syncthreads();

    float om1 = om, om2v = om1 * om1, om4 = om2v * om2v, om8 = om4 * om4, om16 = om8 * om8;
    float pl   = powf(om, (float)(lane + 1));
    float fpre = powf(om, (float)((lane & 15) + 1));
    bool isr1 = (lane >> 4) == 1, isr2 = (lane >> 4) == 2, isr3 = (lane >> 4) == 3;

#define SCAN(QOUT, XV, RSV) { \
    float q_ = a * (XV) * (RSV); \
    DPP_STEP(q_, 0x111, om1); \
    DPP_STEP(q_, 0x112, om2v); \
    DPP_STEP(q_, 0x114, om4); \
    DPP_STEP(q_, 0x118, om8); \
    float e0_ = readlane_f(q_, 15); \
    float e1_ = readlane_f(q_, 31); \
    float e2_ = readlane_f(q_, 47); \
    float t2_ = fmaf(om16, e0_, e1_); \
    float t3_ = fmaf(om16, t2_, e2_); \
    float pre_ = isr1 ? e0_ : (isr2 ? t2_ : (isr3 ? t3_ : 0.f)); \
    QOUT = fmaf(fpre, pre_, q_); }

#define XLOAD(I) float xr##I = x[1 + 64 * I + lane];
    XLOAD(0) XLOAD(1) XLOAD(2) XLOAD(3) XLOAD(4) XLOAD(5) XLOAD(6) XLOAD(7)
    XLOAD(8) XLOAD(9) XLOAD(10) XLOAD(11) XLOAD(12) XLOAD(13) XLOAD(14) XLOAD(15)
#undef XLOAD

    // prologue: seas chunk 0; scan chunk 0; issue read for chunk 1
    float sA0 = ring[1 + lane];
    float Qcur; SCAN(Qcur, xr0, __builtin_amdgcn_rcpf(sA0));
    float sW = sA0;
    float ldsA = ring[65 + lane];   // seas chunk 1 (consumed iter 0)
    float ldsB;
    int ib = 1;

    // iter k: propagate chunk k; ring-write w(k); issue ring-read for chunk k+2 (-> LOUT);
    //         scan chunk k+1 from LIN (read issued last iter); prefetch x chunk k+16.
#define BODY(R, RN, LIN, LOUT) { \
    float lvl = fmaf(pl, lpv, Qcur); \
    lpv = readlane_f(lvl, 63); \
    levels[ib + lane] = lvl; \
    float w_ = fmaf(omg, sW, (g * xr##R) * __builtin_amdgcn_rcpf(lvl)); \
    seas_full[S_LEN + ib + lane] = w_; \
    ring[(ib + S_LEN + lane) & 255] = w_; \
    LOUT = ring[(ib + 128 + lane) & 255]; \
    float rsn_ = __builtin_amdgcn_rcpf(LIN); \
    float Qn_; SCAN(Qn_, xr##RN, rsn_); \
    int pidx = ib + 1024 + lane; pidx = pidx > (T_LEN - 1) ? (T_LEN - 1) : pidx; \
    xr##R = x[pidx]; \
    Qcur = Qn_; sW = LIN; \
    ib += 64; }

    for (int kb = 0; kb < 48; ++kb) {   // 48*16 = 768 iters
        BODY(0,1,  ldsA, ldsB) BODY(1,2,  ldsB, ldsA) BODY(2,3,  ldsA, ldsB) BODY(3,4,  ldsB, ldsA)
        BODY(4,5,  ldsA, ldsB) BODY(5,6,  ldsB, ldsA) BODY(6,7,  ldsA, ldsB) BODY(7,8,  ldsB, ldsA)
        BODY(8,9,  ldsA, ldsB) BODY(9,10, ldsB, ldsA) BODY(10,11,ldsA, ldsB) BODY(11,12,ldsB, ldsA)
        BODY(12,13,ldsA, ldsB) BODY(13,14,ldsB, ldsA) BODY(14,15,ldsA, ldsB) BODY(15,0, ldsB, ldsA)
    }
    // 12 tail iters: k = 768..779
    BODY(0,1,  ldsA, ldsB) BODY(1,2,  ldsB, ldsA) BODY(2,3,  ldsA, ldsB) BODY(3,4,  ldsB, ldsA)
    BODY(4,5,  ldsA, ldsB) BODY(5,6,  ldsB, ldsA) BODY(6,7,  ldsA, ldsB) BODY(7,8,  ldsB, ldsA)
    BODY(8,9,  ldsA, ldsB) BODY(9,10, ldsB, ldsA) BODY(10,11,ldsA, ldsB) BODY(11,12,ldsB, ldsA)
#undef BODY

    {   // propagate chunk 780 (steps 49921..49984; sW = seas(780), Qcur = Q(780))
        float lvl = fmaf(pl, lpv, Qcur);
        lpv = readlane_f(lvl, 63);
        levels[49921 + lane] = lvl;
        float w_ = fmaf(omg, sW, (g * xr12) * __builtin_amdgcn_rcpf(lvl));
        seas_full[S_LEN + 49921 + lane] = w_;
    }
    {   // chunk 781 (steps 49985..49999, lanes 0..14; ldsA = seas(781) pending)
        float rsn_ = __builtin_amdgcn_rcpf(ldsA);
        float Qn_; SCAN(Qn_, xr13, rsn_);
        float lvl = fmaf(pl, lpv, Qn_);
        if (lane < 15) {
            levels[49985 + lane] = lvl;
            float w_ = fmaf(omg, ldsA, (g * xr13) * __builtin_amdgcn_rcpf(lvl));
            seas_full[S_LEN + 49985 + lane] = w_;
        }
    }
#undef SCAN
}

// ---------------- logs + loss partials: F, llev, and per-block sum of d^2 -------------------
__global__ void k_logs(const float* __restrict__ x, const float* __restrict__ levels,
                       const float* __restrict__ seas_full,
                       float* __restrict__ F, float* __restrict__ llev,
                       float* __restrict__ partials) {
    __shared__ float sm[258];
    __shared__ float red[256];
    int tid = threadIdx.x;
    int t = blockIdx.x * 256 + tid;
    float ll = 0.f;
    if (t < T_LEN) {
        F[t]  = __logf(x[t]) - __logf(seas_full[t]);
        ll    = __logf(levels[t]);
        llev[t] = ll;
    }
    sm[tid] = ll;
    if (tid < 2) {
        int te = blockIdx.x * 256 + 256 + tid;
        sm[256 + tid] = (te < T_LEN) ? __logf(levels[te]) : 0.f;
    }
    __syncthreads();
    float s = 0.f;
    if (t < T_LEN - 2) {
        float d = sm[tid + 2] - 2.f * sm[tid + 1] + sm[tid];
        s = d * d;
    }
    red[tid] = s; __syncthreads();
    for (int off = 128; off > 0; off >>= 1) {
        if (tid < off) red[tid] += red[tid + off];
        __syncthreads();
    }
    if (tid == 0) partials[blockIdx.x] = red[0];
}

// ---------------- fused GEMM: barrier-free K-loop, W1 global->reg, 3 blocks/CU --------------
__global__ __launch_bounds__(256, 3) void k_gemm(
        const float* __restrict__ noise, const float* __restrict__ F,
        const float* __restrict__ llev, const short* __restrict__ W1T,
        const float* __restrict__ b1, const short* __restrict__ W2T,
        const float* __restrict__ b2, const float* __restrict__ partials,
        const int* __restrict__ lvp, float* __restrict__ out,
        float* __restrict__ labels, float* __restrict__ loss) {
    __shared__ __align__(16) short hlds[64][360];   // 46080 B (cols 336..351 exact zeros)
    __shared__ __align__(16) float Flds[448];
    __shared__ __align__(16) float Llds[64];
    __shared__ __align__(16) float b1lds[352];      // total 49536 B -> 3 blocks/CU

    int t = threadIdx.x, w = t >> 6, l = t & 63;
    int lm = l & 15, lq = l >> 4;
    long n0 = (long)blockIdx.x * 64;

    // loss final (block 0, wave 3) — independent, no extra barriers
    if (blockIdx.x == 0 && w == 3) {
        float s = partials[l] + partials[l + 64] + partials[l + 128];
        if (l < 4) s += partials[l + 192];
#pragma unroll
        for (int off = 32; off > 0; off >>= 1) s += __shfl_down(s, off, 64);
        if (l == 0) loss[0] = s / (float)(T_LEN - 2) * (float)lvp[0];
    }

    // stage Flds / Llds / b1lds
    if (t < 112)      *(f32x4*)&Flds[t * 4] = *(const f32x4*)&F[n0 + t * 4];
    else if (t < 128) *(f32x4*)&Llds[(t - 112) * 4] = *(const f32x4*)&llev[n0 + W_IN + (t - 112) * 4];
    else if (t < 216) {
        int i4 = (t - 128) * 4;
        f32x4 v = (f32x4){0.f, 0.f, 0.f, 0.f};
        if (i4 < W_IN) v = *(const f32x4*)&b1[i4];
        *(f32x4*)&b1lds[i4] = v;
    }

    int rbase = (w >> 1) * 32;     // sample-row base (2 waves share j-halves)
    int jbase = (w & 1) * 176;     // j base
    long an0 = n0 + rbase + lm, an1 = an0 + 16;
    const long amax = (long)N_ROWS * W_IN - 8;
    long a00 = an0 * W_IN, a10 = an1 * W_IN;

    // prefetch noise ks=0
    long p0 = a00 + lq * 8; if (p0 > amax) p0 = amax;
    long p1 = a10 + lq * 8; if (p1 > amax) p1 = amax;
    f32x4 nc00 = *(const f32x4*)&noise[p0], nc01 = *(const f32x4*)&noise[p0 + 4];
    f32x4 nc10 = *(const f32x4*)&noise[p1], nc11 = *(const f32x4*)&noise[p1 + 4];

    f32x4 acc0[11], acc1[11];
#pragma unroll
    for (int c = 0; c < 11; ++c) { acc0[c] = (f32x4){0,0,0,0}; acc1[c] = (f32x4){0,0,0,0}; }

    __syncthreads();
    float lv0 = Llds[rbase + lm], lv1 = Llds[rbase + 16 + lm];

    // K-loop: NO barriers, NO LDS staging for W1 — af fragments straight from global
    // (wave pairs share the same jbase half -> L1 reuse; per-ks slice 22 KB fits L1).
    const short* w1row = &W1T[(jbase + lm) * 352 + lq * 8];
#pragma unroll 1
    for (int ks = 0; ks < 11; ++ks) {
        // issue af loads (11 x 16B, L1/L2)
        s16x8 af[11];
#pragma unroll
        for (int ct = 0; ct < 11; ++ct)
            af[ct] = *(const s16x8*)&w1row[ct * 16 * 352 + ks * 32];
        // issue noise loads for ks+1
        f32x4 nn00, nn01, nn10, nn11;
        if (ks < 10) {
            int kb = (ks + 1) * 32 + lq * 8;
            long q0 = a00 + kb; if (q0 > amax) q0 = amax;
            long q1 = a10 + kb; if (q1 > amax) q1 = amax;
            nn00 = *(const f32x4*)&noise[q0]; nn01 = *(const f32x4*)&noise[q0 + 4];
            nn10 = *(const f32x4*)&noise[q1]; nn11 = *(const f32x4*)&noise[q1 + 4];
        }
        // build inp fragments (B operand) in registers — covers af latency with VALU
        int fb = rbase + lm + ks * 32 + lq * 8;
        s16x8 bf0, bf1;
#pragma unroll
        for (int j = 0; j < 8; ++j) {
            float nv0 = (j < 4) ? nc00[j] : nc01[j - 4];
            float nv1 = (j < 4) ? nc10[j] : nc11[j - 4];
            bf0[j] = f2bf(Flds[fb + j]      - lv0 + nv0);
            bf1[j] = f2bf(Flds[fb + 16 + j] - lv1 + nv1);
        }
        // MFMA: acc = W1frag * inpfrag  (h comes out transposed)
#pragma unroll
        for (int ct = 0; ct < 11; ++ct) {
            acc0[ct] = __builtin_amdgcn_mfma_f32_16x16x32_bf16(af[ct], bf0, acc0[ct], 0, 0, 0);
            acc1[ct] = __builtin_amdgcn_mfma_f32_16x16x32_bf16(af[ct], bf1, acc1[ct], 0, 0, 0);
        }
        nc00 = nn00; nc01 = nn01; nc10 = nn10; nc11 = nn11;
    }

    // epilogue 1: bias + tanh -> hlds (stride 360; cols 336..351 get exact zeros via
    // zero-padded W1T rows + zero b1lds -> tanh(0)=0)
#pragma unroll
    for (int ct = 0; ct < 11; ++ct) {
        f32x4 b1q = *(f32x4*)&b1lds[jbase + ct * 16 + lq * 4];
        s16x4 h0, h1;
#pragma unroll
        for (int r = 0; r < 4; ++r) {
            h0[r] = f2bf(fast_tanh(acc0[ct][r] + b1q[r]));
            h1[r] = f2bf(fast_tanh(acc1[ct][r] + b1q[r]));
        }
        *(s16x4*)&hlds[rbase + lm][jbase + ct * 16 + lq * 4]      = h0;
        *(s16x4*)&hlds[rbase + 16 + lm][jbase + ct * 16 + lq * 4] = h1;
    }
    __syncthreads();

    // gemm2: out-tile = h @ W2 (W2 fragments direct from global; L1/L2-hot)
    f32x4 a2[3];
    a2[0] = (f32x4){0,0,0,0}; a2[1] = (f32x4){0,0,0,0}; a2[2] = (f32x4){0,0,0,0};
#pragma unroll
    for (int ks = 0; ks < 11; ++ks) {
        s16x8 af2 = *(s16x8*)&hlds[w * 16 + lm][ks * 32 + lq * 8];
#pragma unroll
        for (int ct = 0; ct < 3; ++ct) {
            s16x8 bf2 = *(const s16x8*)&W2T[(ct * 16 + lm) * 360 + ks * 32 + lq * 8];
            a2[ct] = __builtin_amdgcn_mfma_f32_16x16x32_bf16(af2, bf2, a2[ct], 0, 0, 0);
        }
    }

    // epilogue 2: out + labels (labels entirely from LDS)
    int rloc = w * 16 + lq * 4;
#pragma unroll
    for (int ct = 0; ct < 3; ++ct) {
        float b2v = b2[ct * 16 + lm];
#pragma unroll
        for (int r = 0; r < 4; ++r) {
            long row = n0 + rloc + r;
            if (row < N_ROWS) {
                int col = ct * 16 + lm;
                out[row * O_OUT + col]    = a2[ct][r] + b2v;
                labels[row * O_OUT + col] = Flds[rloc + r + W_IN + col] - Llds[rloc + r];
            }
        }
    }
}

extern "C" void kernel_launch(void* const* d_in, const int* in_sizes, int n_in,
                              void* d_out, int out_size, void* d_ws, size_t ws_size,
                              hipStream_t stream) {
    const float* x         = (const float*)d_in[0];
    const float* noise     = (const float*)d_in[1];
    const float* level_sc  = (const float*)d_in[2];
    const float* seas_sc   = (const float*)d_in[3];
    const float* init_seas = (const float*)d_in[4];
    const float* W1        = (const float*)d_in[5];
    const float* b1        = (const float*)d_in[6];
    const float* W2        = (const float*)d_in[7];
    const float* b2        = (const float*)d_in[8];
    const int*   lvp       = (const int*)d_in[11];

    float* out    = (float*)d_out;
    float* labels = out + (long)N_ROWS * O_OUT;
    float* loss   = labels + (long)N_ROWS * O_OUT;

    float* wsf       = (float*)d_ws;
    float* levels    = wsf;               // 50000 (reserve 50048)
    float* seas_full = wsf + 50048;       // 50168 (reserve 50176)
    float* F         = wsf + 100224;      // 50000 (reserve 50176; gemm reads to n0+447)
    float* llev      = wsf + 150400;      // 50000 (reserve 50048)
    float* partials  = wsf + 200448;      // 196   (reserve 256)
    short* W1T       = (short*)(wsf + 200704);   // 352*352 bf16 (zero-padded)
    short* W2T       = W1T + 352 * 352;          // 48*360 bf16

    k_preconvert<<<552, 256, 0, stream>>>(W1, W2, W1T, W2T);
    k_scan<<<1, 64, 0, stream>>>(x, level_sc, seas_sc, init_seas, levels, seas_full);
    k_logs<<<196, 256, 0, stream>>>(x, levels, seas_full, F, llev, partials);
    k_gemm<<<NBLK, 256, 0, stream>>>(noise, F, llev, W1T, b1, W2T, b2,
                                     partials, lvp, out, labels, loss);
}

// Round 7
// 156.024 us; speedup vs baseline: 1.1080x; 1.1080x over previous
//
#include <hip/hip_runtime.h>

typedef __attribute__((ext_vector_type(8))) short  s16x8;   // 8 x bf16
typedef __attribute__((ext_vector_type(4))) short  s16x4;
typedef __attribute__((ext_vector_type(4))) float  f32x4;

#define T_LEN 50000
#define S_LEN 168
#define W_IN  336
#define O_OUT 48
#define N_ROWS (T_LEN - W_IN - O_OUT + 1)   // 49617
#define N_PAD  49664                        // 776 * 64
#define NBLK   (N_PAD / 64)                 // 776

__device__ inline short f2bf(float f) {
    union { float f; unsigned u; } v; v.f = f;
    unsigned u = v.u;
    unsigned r = u + 0x7fffu + ((u >> 16) & 1u);   // RNE
    return (short)(r >> 16);
}

__device__ inline float readlane_f(float v, int l) {
    return __int_as_float(__builtin_amdgcn_readlane(__float_as_int(v), l));
}

__device__ inline float fast_tanh(float v) {
    float e = __expf(2.f * v);
    return 1.f - 2.f * __builtin_amdgcn_rcpf(e + 1.f);
}

// ---------------- pre-convert W1 -> W1T bf16 [352][352] (zero-padded), W2 -> W2T [48][360] --
__global__ void k_preconvert(const float* __restrict__ W1, const float* __restrict__ W2,
                             short* __restrict__ W1T, short* __restrict__ W2T) {
    int idx = blockIdx.x * 256 + threadIdx.x;
    const int n1 = 352 * 352;
    const int tot = n1 + 48 * 360;
    if (idx >= tot) return;
    if (idx < n1) {
        int j = idx / 352, k = idx % 352;
        W1T[idx] = (j < 336 && k < 336) ? f2bf(W1[k * 336 + j]) : (short)0;
    } else {
        int i2 = idx - n1;
        int o = i2 / 360, k = i2 % 360;
        W2T[i2] = (k < 336) ? f2bf(W2[k * 48 + o]) : (short)0;
    }
}

// ---------------- scan: chunk-64, ping-pong LDS regs, w-only ring, DPP scan ----------------
#define DPP_STEP(q_, CTRL, OMW) { \
    int t_ = __builtin_amdgcn_update_dpp(0, __float_as_int(q_), (CTRL), 0xf, 0xf, true); \
    q_ = fmaf((OMW), __int_as_float(t_), q_); }

__global__ void k_scan(const float* __restrict__ x, const float* __restrict__ level_sc,
                       const float* __restrict__ seas_sc, const float* __restrict__ init_seas,
                       float* __restrict__ levels, float* __restrict__ seas_full) {
    __shared__ float ring[256];      // ring[s & 255] = seas(s)
    int lane = threadIdx.x;          // 64 threads, 1 wave
    float a = 1.f / (1.f + expf(-level_sc[0]));
    float g = 1.f / (1.f + expf(-seas_sc[0]));
    float om = 1.f - a, omg = 1.f - g;

    for (int t = lane; t < 256; t += 64) {
        float s = 1.f;
        if (t <= S_LEN) { s = expf(init_seas[t < S_LEN ? t : 0]); seas_full[t] = s; }
        ring[t] = s;
    }
    float lpv = x[0] / expf(init_seas[0]);
    if (lane == 0) levels[0] = lpv;
    __syncthreads();

    float om1 = om, om2v = om1 * om1, om4 = om2v * om2v, om8 = om4 * om4, om16 = om8 * om8;
    float pl   = powf(om, (float)(lane + 1));
    float fpre = powf(om, (float)((lane & 15) + 1));
    bool isr1 = (lane >> 4) == 1, isr2 = (lane >> 4) == 2, isr3 = (lane >> 4) == 3;

#define SCAN(QOUT, XV, RSV) { \
    float q_ = a * (XV) * (RSV); \
    DPP_STEP(q_, 0x111, om1); \
    DPP_STEP(q_, 0x112, om2v); \
    DPP_STEP(q_, 0x114, om4); \
    DPP_STEP(q_, 0x118, om8); \
    float e0_ = readlane_f(q_, 15); \
    float e1_ = readlane_f(q_, 31); \
    float e2_ = readlane_f(q_, 47); \
    float t2_ = fmaf(om16, e0_, e1_); \
    float t3_ = fmaf(om16, t2_, e2_); \
    float pre_ = isr1 ? e0_ : (isr2 ? t2_ : (isr3 ? t3_ : 0.f)); \
    QOUT = fmaf(fpre, pre_, q_); }

#define XLOAD(I) float xr##I = x[1 + 64 * I + lane];
    XLOAD(0) XLOAD(1) XLOAD(2) XLOAD(3) XLOAD(4) XLOAD(5) XLOAD(6) XLOAD(7)
    XLOAD(8) XLOAD(9) XLOAD(10) XLOAD(11) XLOAD(12) XLOAD(13) XLOAD(14) XLOAD(15)
#undef XLOAD

    // prologue: seas chunk 0; scan chunk 0; issue read for chunk 1
    float sA0 = ring[1 + lane];
    float Qcur; SCAN(Qcur, xr0, __builtin_amdgcn_rcpf(sA0));
    float sW = sA0;
    float ldsA = ring[65 + lane];   // seas chunk 1 (consumed iter 0)
    float ldsB;
    int ib = 1;

    // iter k: propagate chunk k; ring-write w(k); issue ring-read for chunk k+2 (-> LOUT);
    //         scan chunk k+1 from LIN (read issued last iter); prefetch x chunk k+16.
#define BODY(R, RN, LIN, LOUT) { \
    float lvl = fmaf(pl, lpv, Qcur); \
    lpv = readlane_f(lvl, 63); \
    levels[ib + lane] = lvl; \
    float w_ = fmaf(omg, sW, (g * xr##R) * __builtin_amdgcn_rcpf(lvl)); \
    seas_full[S_LEN + ib + lane] = w_; \
    ring[(ib + S_LEN + lane) & 255] = w_; \
    LOUT = ring[(ib + 128 + lane) & 255]; \
    float rsn_ = __builtin_amdgcn_rcpf(LIN); \
    float Qn_; SCAN(Qn_, xr##RN, rsn_); \
    int pidx = ib + 1024 + lane; pidx = pidx > (T_LEN - 1) ? (T_LEN - 1) : pidx; \
    xr##R = x[pidx]; \
    Qcur = Qn_; sW = LIN; \
    ib += 64; }

    for (int kb = 0; kb < 48; ++kb) {   // 48*16 = 768 iters
        BODY(0,1,  ldsA, ldsB) BODY(1,2,  ldsB, ldsA) BODY(2,3,  ldsA, ldsB) BODY(3,4,  ldsB, ldsA)
        BODY(4,5,  ldsA, ldsB) BODY(5,6,  ldsB, ldsA) BODY(6,7,  ldsA, ldsB) BODY(7,8,  ldsB, ldsA)
        BODY(8,9,  ldsA, ldsB) BODY(9,10, ldsB, ldsA) BODY(10,11,ldsA, ldsB) BODY(11,12,ldsB, ldsA)
        BODY(12,13,ldsA, ldsB) BODY(13,14,ldsB, ldsA) BODY(14,15,ldsA, ldsB) BODY(15,0, ldsB, ldsA)
    }
    // 12 tail iters: k = 768..779
    BODY(0,1,  ldsA, ldsB) BODY(1,2,  ldsB, ldsA) BODY(2,3,  ldsA, ldsB) BODY(3,4,  ldsB, ldsA)
    BODY(4,5,  ldsA, ldsB) BODY(5,6,  ldsB, ldsA) BODY(6,7,  ldsA, ldsB) BODY(7,8,  ldsB, ldsA)
    BODY(8,9,  ldsA, ldsB) BODY(9,10, ldsB, ldsA) BODY(10,11,ldsA, ldsB) BODY(11,12,ldsB, ldsA)
#undef BODY

    {   // propagate chunk 780 (steps 49921..49984; sW = seas(780), Qcur = Q(780))
        float lvl = fmaf(pl, lpv, Qcur);
        lpv = readlane_f(lvl, 63);
        levels[49921 + lane] = lvl;
        float w_ = fmaf(omg, sW, (g * xr12) * __builtin_amdgcn_rcpf(lvl));
        seas_full[S_LEN + 49921 + lane] = w_;
    }
    {   // chunk 781 (steps 49985..49999, lanes 0..14; ldsA = seas(781) pending)
        float rsn_ = __builtin_amdgcn_rcpf(ldsA);
        float Qn_; SCAN(Qn_, xr13, rsn_);
        float lvl = fmaf(pl, lpv, Qn_);
        if (lane < 15) {
            levels[49985 + lane] = lvl;
            float w_ = fmaf(omg, ldsA, (g * xr13) * __builtin_amdgcn_rcpf(lvl));
            seas_full[S_LEN + 49985 + lane] = w_;
        }
    }
#undef SCAN
}

// ---------------- logs + loss partials: F, llev, and per-block sum of d^2 -------------------
__global__ void k_logs(const float* __restrict__ x, const float* __restrict__ levels,
                       const float* __restrict__ seas_full,
                       float* __restrict__ F, float* __restrict__ llev,
                       float* __restrict__ partials) {
    __shared__ float sm[258];
    __shared__ float red[256];
    int tid = threadIdx.x;
    int t = blockIdx.x * 256 + tid;
    float ll = 0.f;
    if (t < T_LEN) {
        F[t]  = __logf(x[t]) - __logf(seas_full[t]);
        ll    = __logf(levels[t]);
        llev[t] = ll;
    }
    sm[tid] = ll;
    if (tid < 2) {
        int te = blockIdx.x * 256 + 256 + tid;
        sm[256 + tid] = (te < T_LEN) ? __logf(levels[te]) : 0.f;
    }
    __syncthreads();
    float s = 0.f;
    if (t < T_LEN - 2) {
        float d = sm[tid + 2] - 2.f * sm[tid + 1] + sm[tid];
        s = d * d;
    }
    red[tid] = s; __syncthreads();
    for (int off = 128; off > 0; off >>= 1) {
        if (tid < off) red[tid] += red[tid + off];
        __syncthreads();
    }
    if (tid == 0) partials[blockIdx.x] = red[0];
}

// ---------------- fused GEMM: barrier-free K-loop, rolling af regs (no spill) ---------------
__global__ __launch_bounds__(256, 3) void k_gemm(
        const float* __restrict__ noise, const float* __restrict__ F,
        const float* __restrict__ llev, const short* __restrict__ W1T,
        const float* __restrict__ b1, const short* __restrict__ W2T,
        const float* __restrict__ b2, const float* __restrict__ partials,
        const int* __restrict__ lvp, float* __restrict__ out,
        float* __restrict__ labels, float* __restrict__ loss) {
    __shared__ __align__(16) short hlds[64][360];   // 46080 B (cols 336..351 exact zeros)
    __shared__ __align__(16) float Flds[448];
    __shared__ __align__(16) float Llds[64];
    __shared__ __align__(16) float b1lds[352];      // total 49536 B -> 3 blocks/CU

    int t = threadIdx.x, w = t >> 6, l = t & 63;
    int lm = l & 15, lq = l >> 4;
    long n0 = (long)blockIdx.x * 64;

    // loss final (block 0, wave 3) — independent, no extra barriers
    if (blockIdx.x == 0 && w == 3) {
        float s = partials[l] + partials[l + 64] + partials[l + 128];
        if (l < 4) s += partials[l + 192];
#pragma unroll
        for (int off = 32; off > 0; off >>= 1) s += __shfl_down(s, off, 64);
        if (l == 0) loss[0] = s / (float)(T_LEN - 2) * (float)lvp[0];
    }

    // stage Flds / Llds / b1lds
    if (t < 112)      *(f32x4*)&Flds[t * 4] = *(const f32x4*)&F[n0 + t * 4];
    else if (t < 128) *(f32x4*)&Llds[(t - 112) * 4] = *(const f32x4*)&llev[n0 + W_IN + (t - 112) * 4];
    else if (t < 216) {
        int i4 = (t - 128) * 4;
        f32x4 v = (f32x4){0.f, 0.f, 0.f, 0.f};
        if (i4 < W_IN) v = *(const f32x4*)&b1[i4];
        *(f32x4*)&b1lds[i4] = v;
    }

    int rbase = (w >> 1) * 32;     // sample-row base (2 waves share j-halves)
    int jbase = (w & 1) * 176;     // j base
    long an0 = n0 + rbase + lm, an1 = an0 + 16;
    const long amax = (long)N_ROWS * W_IN - 8;
    long a00 = an0 * W_IN, a10 = an1 * W_IN;

    // prefetch noise ks=0
    long p0 = a00 + lq * 8; if (p0 > amax) p0 = amax;
    long p1 = a10 + lq * 8; if (p1 > amax) p1 = amax;
    f32x4 nc00 = *(const f32x4*)&noise[p0], nc01 = *(const f32x4*)&noise[p0 + 4];
    f32x4 nc10 = *(const f32x4*)&noise[p1], nc11 = *(const f32x4*)&noise[p1 + 4];

    f32x4 acc0[11], acc1[11];
#pragma unroll
    for (int c = 0; c < 11; ++c) { acc0[c] = (f32x4){0,0,0,0}; acc1[c] = (f32x4){0,0,0,0}; }

    __syncthreads();
    float lv0 = Llds[rbase + lm], lv1 = Llds[rbase + 16 + lm];

    // K-loop: NO barriers, NO LDS staging for W1; af in 3 rolling regs (no spill).
    const short* w1row = &W1T[(jbase + lm) * 352 + lq * 8];
#define LDW(CT) (*(const s16x8*)&w1row[(CT) * 16 * 352 + ks * 32])
#pragma unroll 1
    for (int ks = 0; ks < 11; ++ks) {
        // build inp fragments first (consumes nc; nc dead after this)
        int fb = rbase + lm + ks * 32 + lq * 8;
        s16x8 bf0, bf1;
#pragma unroll
        for (int j = 0; j < 8; ++j) {
            float nv0 = (j < 4) ? nc00[j] : nc01[j - 4];
            float nv1 = (j < 4) ? nc10[j] : nc11[j - 4];
            bf0[j] = f2bf(Flds[fb + j]      - lv0 + nv0);
            bf1[j] = f2bf(Flds[fb + 16 + j] - lv1 + nv1);
        }
        // issue noise prefetch for ks+1 into the same regs (in flight during MFMAs)
        if (ks < 10) {
            int kb = (ks + 1) * 32 + lq * 8;
            long q0 = a00 + kb; if (q0 > amax) q0 = amax;
            long q1 = a10 + kb; if (q1 > amax) q1 = amax;
            nc00 = *(const f32x4*)&noise[q0]; nc01 = *(const f32x4*)&noise[q0 + 4];
            nc10 = *(const f32x4*)&noise[q1]; nc11 = *(const f32x4*)&noise[q1 + 4];
        }
        // MFMA ct-chain with 3 rolling af regs (depth-3 pipeline, all static names)
        s16x8 af0 = LDW(0), af1 = LDW(1), af2 = LDW(2);
#define MM2(CT, AF) \
        acc0[CT] = __builtin_amdgcn_mfma_f32_16x16x32_bf16(AF, bf0, acc0[CT], 0, 0, 0); \
        acc1[CT] = __builtin_amdgcn_mfma_f32_16x16x32_bf16(AF, bf1, acc1[CT], 0, 0, 0);
        MM2(0, af0)  af0 = LDW(3);
        MM2(1, af1)  af1 = LDW(4);
        MM2(2, af2)  af2 = LDW(5);
        MM2(3, af0)  af0 = LDW(6);
        MM2(4, af1)  af1 = LDW(7);
        MM2(5, af2)  af2 = LDW(8);
        MM2(6, af0)  af0 = LDW(9);
        MM2(7, af1)  af1 = LDW(10);
        MM2(8, af2)
        MM2(9, af0)
        MM2(10, af1)
#undef MM2
    }
#undef LDW

    // epilogue 1: bias + tanh -> hlds (stride 360; cols 336..351 get exact zeros via
    // zero-padded W1T rows + zero b1lds -> tanh(0)=0)
#pragma unroll
    for (int ct = 0; ct < 11; ++ct) {
        f32x4 b1q = *(f32x4*)&b1lds[jbase + ct * 16 + lq * 4];
        s16x4 h0, h1;
#pragma unroll
        for (int r = 0; r < 4; ++r) {
            h0[r] = f2bf(fast_tanh(acc0[ct][r] + b1q[r]));
            h1[r] = f2bf(fast_tanh(acc1[ct][r] + b1q[r]));
        }
        *(s16x4*)&hlds[rbase + lm][jbase + ct * 16 + lq * 4]      = h0;
        *(s16x4*)&hlds[rbase + 16 + lm][jbase + ct * 16 + lq * 4] = h1;
    }
    __syncthreads();

    // gemm2: out-tile = h @ W2 (W2 fragments direct from global; L1/L2-hot)
    f32x4 a2[3];
    a2[0] = (f32x4){0,0,0,0}; a2[1] = (f32x4){0,0,0,0}; a2[2] = (f32x4){0,0,0,0};
#pragma unroll
    for (int ks = 0; ks < 11; ++ks) {
        s16x8 af2 = *(s16x8*)&hlds[w * 16 + lm][ks * 32 + lq * 8];
#pragma unroll
        for (int ct = 0; ct < 3; ++ct) {
            s16x8 bf2 = *(const s16x8*)&W2T[(ct * 16 + lm) * 360 + ks * 32 + lq * 8];
            a2[ct] = __builtin_amdgcn_mfma_f32_16x16x32_bf16(af2, bf2, a2[ct], 0, 0, 0);
        }
    }

    // epilogue 2: out + labels (labels entirely from LDS)
    int rloc = w * 16 + lq * 4;
#pragma unroll
    for (int ct = 0; ct < 3; ++ct) {
        float b2v = b2[ct * 16 + lm];
#pragma unroll
        for (int r = 0; r < 4; ++r) {
            long row = n0 + rloc + r;
            if (row < N_ROWS) {
                int col = ct * 16 + lm;
                out[row * O_OUT + col]    = a2[ct][r] + b2v;
                labels[row * O_OUT + col] = Flds[rloc + r + W_IN + col] - Llds[rloc + r];
            }
        }
    }
}

extern "C" void kernel_launch(void* const* d_in, const int* in_sizes, int n_in,
                              void* d_out, int out_size, void* d_ws, size_t ws_size,
                              hipStream_t stream) {
    const float* x         = (const float*)d_in[0];
    const float* noise     = (const float*)d_in[1];
    const float* level_sc  = (const float*)d_in[2];
    const float* seas_sc   = (const float*)d_in[3];
    const float* init_seas = (const float*)d_in[4];
    const float* W1        = (const float*)d_in[5];
    const float* b1        = (const float*)d_in[6];
    const float* W2        = (const float*)d_in[7];
    const float* b2        = (const float*)d_in[8];
    const int*   lvp       = (const int*)d_in[11];

    float* out    = (float*)d_out;
    float* labels = out + (long)N_ROWS * O_OUT;
    float* loss   = labels + (long)N_ROWS * O_OUT;

    float* wsf       = (float*)d_ws;
    float* levels    = wsf;               // 50000 (reserve 50048)
    float* seas_full = wsf + 50048;       // 50168 (reserve 50176)
    float* F         = wsf + 100224;      // 50000 (reserve 50176; gemm reads to n0+447)
    float* llev      = wsf + 150400;      // 50000 (reserve 50048)
    float* partials  = wsf + 200448;      // 196   (reserve 256)
    short* W1T       = (short*)(wsf + 200704);   // 352*352 bf16 (zero-padded)
    short* W2T       = W1T + 352 * 352;          // 48*360 bf16

    k_preconvert<<<552, 256, 0, stream>>>(W1, W2, W1T, W2T);
    k_scan<<<1, 64, 0, stream>>>(x, level_sc, seas_sc, init_seas, levels, seas_full);
    k_logs<<<196, 256, 0, stream>>>(x, levels, seas_full, F, llev, partials);
    k_gemm<<<NBLK, 256, 0, stream>>>(noise, F, llev, W1T, b1, W2T, b2,
                                     partials, lvp, out, labels, loss);
}